// Round 4
// baseline (358.060 us; speedup 1.0000x reference)
//
#include <hip/hip_runtime.h>
#include <math.h>

// SSIM loss, fused single-pass. fp32 [32,1,1024,1024] x2 -> scalar.
// Separable 11x11 Gaussian of 5 fields {a,b,a2,b2,ab}.
// Round-9: deeper load pipeline. r8 post-mortem: dur fits ~125us floor +
// VALU-issue (r5: 75+127, r8: 50+124) => instruction cuts are diminishing;
// the floor is latency serialization. Structure: at each of 74 barrier
// phases, commit() ds_writes registers loaded only ONE phase earlier; the
// compiler's s_waitcnt vmcnt before the ds_write stalls the whole block on
// ~500-900cyc HBM latency minus ~250cyc of phase work, every phase. Fix:
// TWO staging register sets alternating by row parity; phase s commits row
// s+1 (loaded at phase s-2) and issues row s+3 => each load gets 2 full
// phases of slack. Cost +4 VGPR. Everything else identical to r8 (packed
// fp32 VOP3P math, pre-paired weights in kernarg SGPRs, float2-interleaved
// LDS, clamped-address staging).
// Tile 256 cols x 64 rows; grid 4x16x32 = 2048 blocks = 8/CU.

typedef float v2f __attribute__((ext_vector_type(2)));

#define IMG_W 1024
#define IMG_H 1024
#define NIMG  32
#define TW    256
#define TH    64
#define HALO  5
#define KW    11
#define ROWS  (TH + 2*HALO)   // 74 staged rows
#define NSO   7               // 7*11 = 77 unrolled steps, tail guarded off
#define SBP   268             // LDS row stride in v2f (266 used, 16B-pad)

#define C1f (0.01f * 0.01f)
#define C2f (0.03f * 0.03f)

struct GW { v2f wp[KW]; };    // wp[i] = (w[i], w[i]) -- pre-paired for VOP3P

__global__ __launch_bounds__(256, 2)
void ssim_main(const float* __restrict__ img1, const float* __restrict__ img2,
               double* __restrict__ acc_out, GW gw)
{
    alignas(16) __shared__ v2f sb[2][SBP];
    __shared__ float wsum[4];

    const int tid = threadIdx.x;
    const int c0 = blockIdx.x * TW;
    const int r0 = blockIdx.y * TH;
    const size_t imgoff = (size_t)blockIdx.z * (size_t)(IMG_W * IMG_H);
    const float* p1 = img1 + imgoff;
    const float* p2 = img2 + imgoff;

    // column geometry (uniform over rows); addresses clamped, OOB zeroed by select
    const int  gc_m   = c0 - HALO + tid;
    const int  gcc_m  = min(max(gc_m, 0), IMG_W - 1);
    const bool cok_m  = ((unsigned)gc_m < (unsigned)IMG_W);
    const int  gc_h   = c0 - HALO + TW + tid;            // used by tid<10
    const int  gcc_h  = min(max(gc_h, 0), IMG_W - 1);
    const bool cok_h  = (tid < 2 * HALO) && ((unsigned)gc_h < (unsigned)IMG_W);

    // vertical ring: (m1,m2) pairs, (sa,sb) pairs, ab scalar = 55 floats
    v2f  r_m[KW], r_s[KW];
    float r_ab[KW];
#pragma unroll
    for (int j = 0; j < KW; ++j) {
        r_m[j] = (v2f)0.f; r_s[j] = (v2f)0.f; r_ab[j] = 0.f;
    }

    float lsum = 0.0f;

    // TWO staging register sets (row parity): [a_main, b_main, a_halo, b_halo]
    float sA0, sA1, sA2, sA3;   // even rows
    float sB0, sB1, sB2, sB3;   // odd rows

    auto issue = [&](int s) {           // global -> regs (set = s&1) for staged row s
        const int gr  = r0 + s - HALO;
        const bool rok = ((unsigned)gr < (unsigned)IMG_H);
        const size_t rbase = (size_t)min(max(gr, 0), IMG_H - 1) * IMG_W;
        float a0 = p1[rbase + gcc_m];
        float b0 = p2[rbase + gcc_m];
        float a1 = p1[rbase + gcc_h];
        float b1 = p2[rbase + gcc_h];
        const bool okm = rok && cok_m;
        const bool okh = rok && cok_h;
        float t0 = okm ? a0 : 0.f;
        float t1 = okm ? b0 : 0.f;
        float t2 = okh ? a1 : 0.f;
        float t3 = okh ? b1 : 0.f;
        if (s & 1) { sB0 = t0; sB1 = t1; sB2 = t2; sB3 = t3; }
        else       { sA0 = t0; sA1 = t1; sA2 = t2; sA3 = t3; }
    };
    auto commit = [&](int s) {          // regs (set = s&1) -> LDS buffer s&1
        v2f* dst = sb[s & 1];
        v2f t, t2;
        if (s & 1) { t.x = sB0; t.y = sB1; t2.x = sB2; t2.y = sB3; }
        else       { t.x = sA0; t.y = sA1; t2.x = sA2; t2.y = sA3; }
        dst[tid] = t;
        if (tid < 2 * HALO) dst[TW + tid] = t2;
    };

    // prologue: row 0 straight to LDS; rows 1,2 in flight in regs
    issue(0); commit(0);
    issue(1);               // set B (odd)
    issue(2);               // set A (even)

    for (int so = 0; so < NSO; ++so) {
#pragma unroll
        for (int u = 0; u < KW; ++u) {
            const int s = so * KW + u;
            if (s < ROWS) {                 // uniform guard (tail steps dead)
                __syncthreads();            // phase s-1 reads done; buf (s+1)&1 free
                if (s + 1 < ROWS) commit(s + 1);   // loads issued at phase s-2
                if (s + 3 < ROWS) issue(s + 3);    // recycles set just committed
                else if (s + 2 == ROWS - 1 + 1) {} // (no-op; tail handled by guards)

                // horizontal 11-tap conv, packed: hm=(m1,m2) hs=(sa,sb) hab scalar
                const v2f* b = sb[s & 1];
                v2f hm = (v2f)0.f, hs = (v2f)0.f;
                float hab = 0.f;
#pragma unroll
                for (int i = 0; i < KW; ++i) {
                    const v2f E  = b[tid + i];        // (a, b) packed
                    const v2f wv = gw.wp[i];          // (w, w) SGPR pair
                    hm = __builtin_elementwise_fma(wv, E, hm);        // pk_fma
                    const v2f P = E * E;                              // pk_mul
                    hs = __builtin_elementwise_fma(wv, P, hs);        // pk_fma
                    hab = __builtin_fmaf(wv.x, E.x * E.y, hab);       // mul+fma
                }

                // vertical ring accumulate; slot j fresh-starts when k==0
#pragma unroll
                for (int j = 0; j < KW; ++j) {
                    const int k = (u - j + KW) % KW;   // compile-time after unroll
                    const v2f  wv = gw.wp[k];
                    const float wk = wv.x;
                    if (k == 0) {
                        r_m[j] = wv * hm;                              // pk_mul
                        r_s[j] = wv * hs;                              // pk_mul
                        r_ab[j] = wk * hab;
                    } else {
                        r_m[j] = __builtin_elementwise_fma(wv, hm, r_m[j]);
                        r_s[j] = __builtin_elementwise_fma(wv, hs, r_s[j]);
                        r_ab[j] = __builtin_fmaf(wk, hab, r_ab[j]);
                    }
                }

                // output row r = s-10 completes in slot (u+1)%11
                if (s >= 10) {
                    const int je = (u + 1) % KW;
                    const v2f  mu  = r_m[je];          // (mu1, mu2)
                    const v2f  cs  = r_s[je];          // (caa, cbb)
                    const float cab = r_ab[je];
                    const v2f  mus = mu * mu;          // (mu1^2, mu2^2)
                    const float mu12 = mu.x * mu.y;
                    const v2f  sg  = cs - mus;         // (sg1, sg2)
                    const float sg12 = cab - mu12;
                    const float num = (2.0f * mu12 + C1f) * (2.0f * sg12 + C2f);
                    const float den = (mus.x + mus.y + C1f) * (sg.x + sg.y + C2f);
                    lsum = __builtin_fmaf(num, __builtin_amdgcn_rcpf(den), lsum);
                }
            }
        }
    }

    // block reduction: wave shuffle then LDS across the 4 waves
    float v = lsum;
#pragma unroll
    for (int off = 32; off > 0; off >>= 1) v += __shfl_down(v, off);
    __syncthreads();
    if ((tid & 63) == 0) wsum[tid >> 6] = v;
    __syncthreads();
    if (tid == 0) {
        float bsum = wsum[0] + wsum[1] + wsum[2] + wsum[3];
        atomicAdd(acc_out, (double)bsum);
    }
}

__global__ void ssim_finalize(const double* __restrict__ acc, float* __restrict__ out)
{
    out[0] = 1.0f - (float)(acc[0] * (1.0 / ((double)NIMG * IMG_W * IMG_H)));
}

extern "C" void kernel_launch(void* const* d_in, const int* in_sizes, int n_in,
                              void* d_out, int out_size, void* d_ws, size_t ws_size,
                              hipStream_t stream)
{
    const float* img1 = (const float*)d_in[0];
    const float* img2 = (const float*)d_in[1];
    float* out = (float*)d_out;
    double* accbuf = (double*)d_ws;

    // Gaussian weights exactly as the reference: exp in f64, cast f32, normalize
    GW gw;
    {
        float g[KW];
        double s = 0.0;
        for (int i = 0; i < KW; ++i) {
            int x = i - KW / 2;
            g[i] = (float)exp(-(double)(x * x) / (2.0 * 1.5 * 1.5));
            s += (double)g[i];
        }
        for (int i = 0; i < KW; ++i) {
            float w = (float)((double)g[i] / s);
            gw.wp[i].x = w;
            gw.wp[i].y = w;
        }
    }

    hipMemsetAsync(accbuf, 0, sizeof(double), stream);
    dim3 grid(IMG_W / TW, IMG_H / TH, NIMG);
    ssim_main<<<grid, 256, 0, stream>>>(img1, img2, accbuf, gw);
    ssim_finalize<<<1, 1, 0, stream>>>(accbuf, out);
}